// Round 1
// 2355.816 us; speedup vs baseline: 2.5135x; 2.5135x over previous
//
#include <hip/hip_runtime.h>
#include <stdint.h>
#include <stddef.h>

// ---- problem constants ----
#define TT   1024
#define BB   32
#define II   1024
#define HH   1024
#define NHH  8
#define HSS  128
#define N4   4096   // NH*4*HS

typedef _Float16 h8 __attribute__((ext_vector_type(8)));
typedef _Float16 h4 __attribute__((ext_vector_type(4)));
typedef float    f4 __attribute__((ext_vector_type(4)));

// async global->LDS, 16B per lane. LDS dest is wave-uniform base + lane*16.
#define GLDS16(G, L) __builtin_amdgcn_global_load_lds(                      \
    (__attribute__((address_space(1))) void*)(G),                           \
    (__attribute__((address_space(3))) void*)(L), 16, 0, 0)

// ---------------- prep: transpose Whh to [head][k][n], zero states ----------
__global__ void prep_kernel(const float* __restrict__ whh, float* __restrict__ whhT,
                            float* __restrict__ st, float* __restrict__ hst) {
  int idx = blockIdx.x * blockDim.x + threadIdx.x;
  int stride = gridDim.x * blockDim.x;
  // whh flat: [head][n][k], n in [0,512), k in [0,128)
  for (int i = idx; i < NHH * 512 * HSS; i += stride) {
    int head = i >> 16;           // /(512*128)
    int rem = i & 65535;
    int n = rem >> 7, k = rem & 127;
    whhT[(size_t)(head * HSS + k) * 512 + n] = whh[i];
  }
  for (int i = idx; i < 3 * BB * NHH * HSS; i += stride) st[i] = 0.0f;
  for (int i = idx; i < BB * NHH * HSS; i += stride) hst[i] = 0.0f;
}

// ---------------- fp32 -> fp16 hi/lo split (lo pre-scaled by 2^11) ----------
// a = hi + lo/2048 with |err| ~ 2^-23 |a|. Scaling keeps lo in fp16 normal range
// (raw W_ih lo terms ~4e-5 would be subnormal and could FTZ inside MFMA).
__global__ __launch_bounds__(256) void convert_split(
    const float* __restrict__ src, _Float16* __restrict__ hi,
    _Float16* __restrict__ lo, int n4) {
  int idx = blockIdx.x * blockDim.x + threadIdx.x;
  int stride = gridDim.x * blockDim.x;
  for (int i = idx; i < n4; i += stride) {
    const float4 x = *(const float4*)&src[(size_t)i * 4];
    _Float16 h0 = (_Float16)x.x, h1 = (_Float16)x.y,
             h2 = (_Float16)x.z, h3 = (_Float16)x.w;
    _Float16 l0 = (_Float16)((x.x - (float)h0) * 2048.0f);
    _Float16 l1 = (_Float16)((x.y - (float)h1) * 2048.0f);
    _Float16 l2 = (_Float16)((x.z - (float)h2) * 2048.0f);
    _Float16 l3 = (_Float16)((x.w - (float)h3) * 2048.0f);
    h4 hv = {h0, h1, h2, h3};
    h4 lv = {l0, l1, l2, l3};
    *(h4*)&hi[(size_t)i * 4] = hv;
    *(h4*)&lo[(size_t)i * 4] = lv;
  }
}

// ---------------- gates GEMM via split-fp16 MFMA ----------------
// C[m][n] = sum_k A[m][k]*Bt[n][k] + bias[n], fp32-class precision:
//   C = acc1 + acc2/2048, acc1 = Ah*Bh, acc2 = Ah*Bl + Al*Bh  (fp32 MFMA accum)
// m97 structure: 128x128 tile, BK=32, 4 waves (2x2), each wave 64x64 = 4x4
// frags of 16x16x32, global_load_lds width 16, single LDS buffer, 2 barriers.
__global__ __launch_bounds__(256, 2) void gemm_gates_mfma(
    const _Float16* __restrict__ Ah, const _Float16* __restrict__ Al,
    const _Float16* __restrict__ Bh, const _Float16* __restrict__ Bl,
    const float* __restrict__ bias, float* __restrict__ C) {
  __shared__ __align__(16) _Float16 sAh[128 * 32];
  __shared__ __align__(16) _Float16 sAl[128 * 32];
  __shared__ __align__(16) _Float16 sBh[128 * 32];
  __shared__ __align__(16) _Float16 sBl[128 * 32];

  const int tid = threadIdx.x;
  const int lane = tid & 63;
  const int wave = tid >> 6;
  const long r0 = (long)blockIdx.y * 128;
  const long c0 = (long)blockIdx.x * 128;
  const int wr = (wave >> 1) * 64;   // wave's row offset in tile
  const int wc = (wave & 1) * 64;    // wave's col offset in tile

  f4 acc1[4][4], acc2[4][4];
#pragma unroll
  for (int i = 0; i < 4; ++i)
#pragma unroll
    for (int j = 0; j < 4; ++j) { acc1[i][j] = (f4)0.0f; acc2[i][j] = (f4)0.0f; }

  // staging: 256 threads x 16B = 4KB/round = 64 rows; tile = 128 rows = 2 rounds.
  // thread tid covers row tid>>2, half-offset (tid&3)*8 -> LDS image is linear
  // row-major [128][32] fp16 (wave w lanes write w*1024B + lane*16B).
  const int sRow = tid >> 2;
  const int sKh = (tid & 3) * 8;
  const _Float16* gAh = Ah + (r0 + sRow) * 1024 + sKh;
  const _Float16* gAl = Al + (r0 + sRow) * 1024 + sKh;
  const _Float16* gBh = Bh + (c0 + sRow) * 1024 + sKh;
  const _Float16* gBl = Bl + (c0 + sRow) * 1024 + sKh;
  _Float16* lAh = &sAh[sRow * 32 + sKh];
  _Float16* lAl = &sAl[sRow * 32 + sKh];
  _Float16* lBh = &sBh[sRow * 32 + sKh];
  _Float16* lBl = &sBl[sRow * 32 + sKh];

  // MFMA fragment addressing: A row / Bt row = lane&15, k = (lane>>4)*8 .. +7
  const int fRow = lane & 15;
  const int fK = (lane >> 4) * 8;

  for (int kt = 0; kt < 32; ++kt) {
    const int k0 = kt * 32;
    GLDS16(gAh + k0, lAh);
    GLDS16(gAh + k0 + 64 * 1024, lAh + 64 * 32);
    GLDS16(gAl + k0, lAl);
    GLDS16(gAl + k0 + 64 * 1024, lAl + 64 * 32);
    GLDS16(gBh + k0, lBh);
    GLDS16(gBh + k0 + 64 * 1024, lBh + 64 * 32);
    GLDS16(gBl + k0, lBl);
    GLDS16(gBl + k0 + 64 * 1024, lBl + 64 * 32);
    __syncthreads();   // compiler drains vmcnt before s_barrier

    h8 fBh[4], fBl[4];
#pragma unroll
    for (int j = 0; j < 4; ++j) {
      fBh[j] = *(const h8*)&sBh[(wc + j * 16 + fRow) * 32 + fK];
      fBl[j] = *(const h8*)&sBl[(wc + j * 16 + fRow) * 32 + fK];
    }
#pragma unroll
    for (int i = 0; i < 4; ++i) {
      h8 ah = *(const h8*)&sAh[(wr + i * 16 + fRow) * 32 + fK];
      h8 al = *(const h8*)&sAl[(wr + i * 16 + fRow) * 32 + fK];
#pragma unroll
      for (int j = 0; j < 4; ++j) {
        acc1[i][j] = __builtin_amdgcn_mfma_f32_16x16x32_f16(ah, fBh[j], acc1[i][j], 0, 0, 0);
        acc2[i][j] = __builtin_amdgcn_mfma_f32_16x16x32_f16(ah, fBl[j], acc2[i][j], 0, 0, 0);
        acc2[i][j] = __builtin_amdgcn_mfma_f32_16x16x32_f16(al, fBh[j], acc2[i][j], 0, 0, 0);
      }
    }
    __syncthreads();
  }

  // C/D layout (m89-verified): col = lane&15, row = (lane>>4)*4 + reg
  const int rgrp = (lane >> 4) * 4;
#pragma unroll
  for (int j = 0; j < 4; ++j) {
    const long col = c0 + wc + j * 16 + fRow;
    const float bj = bias[col];
#pragma unroll
    for (int i = 0; i < 4; ++i) {
      const long row = r0 + wr + i * 16 + rgrp;
#pragma unroll
      for (int q = 0; q < 4; ++q) {
        C[(row + q) * (long)N4 + col] =
            acc1[i][j][q] + acc2[i][j][q] * (1.0f / 2048.0f) + bj;
      }
    }
  }
}

// ---------------- sequential scan, pure fp32 (unchanged) ----------------
__global__ __launch_bounds__(512) void scan_f32(
    const float* __restrict__ gates, const float* __restrict__ whhT,
    float* __restrict__ out,
    float* __restrict__ stc, float* __restrict__ stn, float* __restrict__ stm,
    float* __restrict__ hst, int t0, int chp) {
  __shared__ float hbuf[128];
  __shared__ float pre[512];
  const int tid = threadIdx.x;
  const int head = blockIdx.x >> 5, b = blockIdx.x & 31;

  float W[128];
#pragma unroll
  for (int k = 0; k < 128; ++k) W[k] = whhT[(size_t)(head * HSS + k) * 512 + tid];

  float c = 0.f, nn = 0.f, m = 0.f;
  if (tid < 128) {
    int si = (b * NHH + head) * HSS + tid;
    c = stc[si]; nn = stn[si]; m = stm[si];
    hbuf[tid] = hst[si];
  }
  __syncthreads();

  const size_t gbase = (size_t)b * N4 + head * 512 + tid;
  float gcur = gates[gbase];

  for (int t = 0; t < chp; ++t) {
    float gnext = 0.0f;
    if (t + 1 < chp) gnext = gates[gbase + (size_t)(t + 1) * 32 * N4];

    float a0 = 0.f, a1 = 0.f;
#pragma unroll
    for (int k4 = 0; k4 < 16; ++k4) {
      float4 h0 = *(const float4*)&hbuf[k4 * 4];
      float4 h1 = *(const float4*)&hbuf[64 + k4 * 4];
      a0 += W[k4 * 4 + 0] * h0.x; a0 += W[k4 * 4 + 1] * h0.y;
      a0 += W[k4 * 4 + 2] * h0.z; a0 += W[k4 * 4 + 3] * h0.w;
      a1 += W[64 + k4 * 4 + 0] * h1.x; a1 += W[64 + k4 * 4 + 1] * h1.y;
      a1 += W[64 + k4 * 4 + 2] * h1.z; a1 += W[64 + k4 * 4 + 3] * h1.w;
    }
    pre[tid] = gcur + (a0 + a1);
    __syncthreads();

    if (tid < 128) {
      float iv = pre[tid], fv = pre[128 + tid], zv = pre[256 + tid], ov = pre[384 + tid];
      float a = fv + m;
      float mn = fmaxf(a, iv);
      float fe = expf(a - mn);
      float ie = expf(iv - mn);
      float zt = tanhf(zv);
      float og = 1.0f / (1.0f + expf(-ov));
      c = fe * c + ie * zt;
      nn = fe * nn + ie;
      m = mn;
      float h = og * (c / nn);
      out[(size_t)(t0 + t) * (BB * HH) + (size_t)b * HH + head * HSS + tid] = h;
      hbuf[tid] = h;
    }
    __syncthreads();
    gcur = gnext;
  }

  if (tid < 128) {
    int si = (b * NHH + head) * HSS + tid;
    stc[si] = c; stn[si] = nn; stm[si] = m;
    hst[si] = hbuf[tid];
  }
}

// ---------------- launcher ----------------
// ws: whhT 2MB | stc/stn/stm 128KB ea | hst 128KB | Bh/Bl 8MB ea |
//     Ah/Al ch*64KB ea | gates ch*512KB
extern "C" void kernel_launch(void* const* d_in, const int* in_sizes, int n_in,
                              void* d_out, int out_size, void* d_ws, size_t ws_size,
                              hipStream_t stream) {
  const float* xs   = (const float*)d_in[0];
  const float* wih  = (const float*)d_in[1];
  const float* whh  = (const float*)d_in[2];
  const float* bias = (const float*)d_in[3];
  float* out = (float*)d_out;
  char* ws = (char*)d_ws;

  float* whhT = (float*)(ws + 0);
  float* stc  = (float*)(ws + 2097152);
  float* stn  = (float*)(ws + 2228224);
  float* stm  = (float*)(ws + 2359296);
  float* hst  = (float*)(ws + 2490368);
  _Float16* Bh = (_Float16*)(ws + 2621440);    // 4096*1024*2 = 8388608
  _Float16* Bl = (_Float16*)(ws + 11010048);   // + 8388608 -> ends 19398656
  const size_t base = 19398656;

  // per-chunk: Ah + Al = ch*131072 B, gates = ch*524288 B
  int ch = 256;
  while (ch > 8 && base + (size_t)ch * 655360 > ws_size) ch >>= 1;
  _Float16* Ahp = (_Float16*)(ws + base);
  _Float16* Alp = (_Float16*)(ws + base + (size_t)ch * 65536);
  float* gts = (float*)(ws + base + (size_t)ch * 131072);
  const int nch = TT / ch;

  prep_kernel<<<256, 256, 0, stream>>>(whh, whhT, stc, hst);
  convert_split<<<1024, 256, 0, stream>>>(wih, Bh, Bl, N4 * II / 4);

  for (int cix = 0; cix < nch; ++cix) {
    convert_split<<<1024, 256, 0, stream>>>(xs + (size_t)cix * ch * BB * II,
                                            Ahp, Alp, ch * BB * II / 4);
    dim3 g(32, (unsigned)(ch * 32 / 128));
    gemm_gates_mfma<<<g, 256, 0, stream>>>(Ahp, Alp, Bh, Bl, bias, gts);
    scan_f32<<<256, 512, 0, stream>>>(gts, whhT, out, stc, stn, stm, hst,
                                      cix * ch, ch);
  }
}

// Round 2
// 2284.522 us; speedup vs baseline: 2.5920x; 1.0312x over previous
//
#include <hip/hip_runtime.h>
#include <stdint.h>
#include <stddef.h>

// ---- problem constants ----
#define TT   1024
#define BB   32
#define II   1024
#define HH   1024
#define NHH  8
#define HSS  128
#define N4   4096   // NH*4*HS

typedef _Float16 h8 __attribute__((ext_vector_type(8)));
typedef _Float16 h4 __attribute__((ext_vector_type(4)));
typedef float    f4 __attribute__((ext_vector_type(4)));

// async global->LDS, 16B per lane. LDS dest is wave-uniform base + lane*16.
#define GLDS16(G, L) __builtin_amdgcn_global_load_lds(                      \
    (__attribute__((address_space(1))) void*)(G),                           \
    (__attribute__((address_space(3))) void*)(L), 16, 0, 0)

// ---------------- prep: transpose Whh to [head][k][n], zero states ----------
__global__ void prep_kernel(const float* __restrict__ whh, float* __restrict__ whhT,
                            float* __restrict__ st, float* __restrict__ hst) {
  int idx = blockIdx.x * blockDim.x + threadIdx.x;
  int stride = gridDim.x * blockDim.x;
  // whh flat: [head][n][k], n in [0,512), k in [0,128)
  for (int i = idx; i < NHH * 512 * HSS; i += stride) {
    int head = i >> 16;           // /(512*128)
    int rem = i & 65535;
    int n = rem >> 7, k = rem & 127;
    whhT[(size_t)(head * HSS + k) * 512 + n] = whh[i];
  }
  for (int i = idx; i < 3 * BB * NHH * HSS; i += stride) st[i] = 0.0f;
  for (int i = idx; i < BB * NHH * HSS; i += stride) hst[i] = 0.0f;
}

// ---------------- fp32 -> fp16 hi/lo split (lo pre-scaled by 2^11) ----------
// a = hi + lo/2048 with |err| ~ 2^-23 |a|. Scaling keeps lo in fp16 normal range
// (raw W_ih lo terms ~4e-5 would be subnormal and could FTZ inside MFMA).
__global__ __launch_bounds__(256) void convert_split(
    const float* __restrict__ src, _Float16* __restrict__ hi,
    _Float16* __restrict__ lo, int n4) {
  int idx = blockIdx.x * blockDim.x + threadIdx.x;
  int stride = gridDim.x * blockDim.x;
  for (int i = idx; i < n4; i += stride) {
    const float4 x = *(const float4*)&src[(size_t)i * 4];
    _Float16 h0 = (_Float16)x.x, h1 = (_Float16)x.y,
             h2 = (_Float16)x.z, h3 = (_Float16)x.w;
    _Float16 l0 = (_Float16)((x.x - (float)h0) * 2048.0f);
    _Float16 l1 = (_Float16)((x.y - (float)h1) * 2048.0f);
    _Float16 l2 = (_Float16)((x.z - (float)h2) * 2048.0f);
    _Float16 l3 = (_Float16)((x.w - (float)h3) * 2048.0f);
    h4 hv = {h0, h1, h2, h3};
    h4 lv = {l0, l1, l2, l3};
    *(h4*)&hi[(size_t)i * 4] = hv;
    *(h4*)&lo[(size_t)i * 4] = lv;
  }
}

// ---------------- gates GEMM via split-fp16 MFMA ----------------
// C[m][n] = sum_k A[m][k]*Bt[n][k] + bias[n], fp32-class precision:
//   C = acc1 + acc2/2048, acc1 = Ah*Bh, acc2 = Ah*Bl + Al*Bh  (fp32 MFMA accum)
// m97 structure: 128x128 tile, BK=32, 4 waves (2x2), each wave 64x64 = 4x4
// frags of 16x16x32, global_load_lds width 16, single LDS buffer, 2 barriers.
__global__ __launch_bounds__(256, 2) void gemm_gates_mfma(
    const _Float16* __restrict__ Ah, const _Float16* __restrict__ Al,
    const _Float16* __restrict__ Bh, const _Float16* __restrict__ Bl,
    const float* __restrict__ bias, float* __restrict__ C) {
  __shared__ __align__(16) _Float16 sAh[128 * 32];
  __shared__ __align__(16) _Float16 sAl[128 * 32];
  __shared__ __align__(16) _Float16 sBh[128 * 32];
  __shared__ __align__(16) _Float16 sBl[128 * 32];

  const int tid = threadIdx.x;
  const int lane = tid & 63;
  const int wave = tid >> 6;
  const long r0 = (long)blockIdx.y * 128;
  const long c0 = (long)blockIdx.x * 128;
  const int wr = (wave >> 1) * 64;   // wave's row offset in tile
  const int wc = (wave & 1) * 64;    // wave's col offset in tile

  f4 acc1[4][4], acc2[4][4];
#pragma unroll
  for (int i = 0; i < 4; ++i)
#pragma unroll
    for (int j = 0; j < 4; ++j) { acc1[i][j] = (f4)0.0f; acc2[i][j] = (f4)0.0f; }

  // staging: 256 threads x 16B = 4KB/round = 64 rows; tile = 128 rows = 2 rounds.
  const int sRow = tid >> 2;
  const int sKh = (tid & 3) * 8;
  const _Float16* gAh = Ah + (r0 + sRow) * 1024 + sKh;
  const _Float16* gAl = Al + (r0 + sRow) * 1024 + sKh;
  const _Float16* gBh = Bh + (c0 + sRow) * 1024 + sKh;
  const _Float16* gBl = Bl + (c0 + sRow) * 1024 + sKh;
  _Float16* lAh = &sAh[sRow * 32 + sKh];
  _Float16* lAl = &sAl[sRow * 32 + sKh];
  _Float16* lBh = &sBh[sRow * 32 + sKh];
  _Float16* lBl = &sBl[sRow * 32 + sKh];

  // MFMA fragment addressing: A row / Bt row = lane&15, k = (lane>>4)*8 .. +7
  const int fRow = lane & 15;
  const int fK = (lane >> 4) * 8;

  for (int kt = 0; kt < 32; ++kt) {
    const int k0 = kt * 32;
    GLDS16(gAh + k0, lAh);
    GLDS16(gAh + k0 + 64 * 1024, lAh + 64 * 32);
    GLDS16(gAl + k0, lAl);
    GLDS16(gAl + k0 + 64 * 1024, lAl + 64 * 32);
    GLDS16(gBh + k0, lBh);
    GLDS16(gBh + k0 + 64 * 1024, lBh + 64 * 32);
    GLDS16(gBl + k0, lBl);
    GLDS16(gBl + k0 + 64 * 1024, lBl + 64 * 32);
    __syncthreads();   // compiler drains vmcnt before s_barrier

    h8 fBh[4], fBl[4];
#pragma unroll
    for (int j = 0; j < 4; ++j) {
      fBh[j] = *(const h8*)&sBh[(wc + j * 16 + fRow) * 32 + fK];
      fBl[j] = *(const h8*)&sBl[(wc + j * 16 + fRow) * 32 + fK];
    }
#pragma unroll
    for (int i = 0; i < 4; ++i) {
      h8 ah = *(const h8*)&sAh[(wr + i * 16 + fRow) * 32 + fK];
      h8 al = *(const h8*)&sAl[(wr + i * 16 + fRow) * 32 + fK];
#pragma unroll
      for (int j = 0; j < 4; ++j) {
        acc1[i][j] = __builtin_amdgcn_mfma_f32_16x16x32_f16(ah, fBh[j], acc1[i][j], 0, 0, 0);
        acc2[i][j] = __builtin_amdgcn_mfma_f32_16x16x32_f16(ah, fBl[j], acc2[i][j], 0, 0, 0);
        acc2[i][j] = __builtin_amdgcn_mfma_f32_16x16x32_f16(al, fBh[j], acc2[i][j], 0, 0, 0);
      }
    }
    __syncthreads();
  }

  // C/D layout (m89-verified): col = lane&15, row = (lane>>4)*4 + reg
  const int rgrp = (lane >> 4) * 4;
#pragma unroll
  for (int j = 0; j < 4; ++j) {
    const long col = c0 + wc + j * 16 + fRow;
    const float bj = bias[col];
#pragma unroll
    for (int i = 0; i < 4; ++i) {
      const long row = r0 + wr + i * 16 + rgrp;
#pragma unroll
      for (int q = 0; q < 4; ++q) {
        C[(row + q) * (long)N4 + col] =
            acc1[i][j][q] + acc2[i][j][q] * (1.0f / 2048.0f) + bj;
      }
    }
  }
}

// ---------------- sequential scan, fp32 VALU ----------------
// 256 blocks = head*32 + b. 512 threads; thread n owns output col n (gate g=n>>7,
// d=n&127). W_hh row pinned in 128 VGPRs — __launch_bounds__(512,2) gives the
// allocator a 256-VGPR budget so W does NOT spill (round-1's VGPR_Count=104
// proved the previous build spilled W to scratch: 512B/thread/step re-read).
// z/o gate transcendentals run on their owner threads pre-barrier (wave-uniform
// branch: waves 4-5 = z, 6-7 = o), so the post-barrier 128-thread phase is only
// max + 2 exp + 2 fma + div.
__device__ __forceinline__ float fast_sigmoid(float x) {
  return 1.0f / (1.0f + __expf(-x));
}
__device__ __forceinline__ float fast_tanh(float x) {
  // 1 - 2/(e^{2x}+1); exact at +-inf overflow, no branches
  return 1.0f - 2.0f / (__expf(2.0f * x) + 1.0f);
}

__global__ __launch_bounds__(512, 2) void scan_f32(
    const float* __restrict__ gates, const float* __restrict__ whhT,
    float* __restrict__ out,
    float* __restrict__ stc, float* __restrict__ stn, float* __restrict__ stm,
    float* __restrict__ hst, int t0, int chp) {
  __shared__ float hbuf[128];
  __shared__ float pre[512];
  const int tid = threadIdx.x;
  const int head = blockIdx.x >> 5, b = blockIdx.x & 31;
  const int g = tid >> 7;   // gate index: 0=i 1=f 2=z 3=o (wave-uniform)

  float W[128];
#pragma unroll
  for (int k = 0; k < 128; ++k) W[k] = whhT[(size_t)(head * HSS + k) * 512 + tid];

  float c = 0.f, nn = 0.f, m = 0.f;
  if (tid < 128) {
    int si = (b * NHH + head) * HSS + tid;
    c = stc[si]; nn = stn[si]; m = stm[si];
    hbuf[tid] = hst[si];
  }
  __syncthreads();

  const size_t gbase = (size_t)b * N4 + head * 512 + tid;
  float gcur = gates[gbase];

  for (int t = 0; t < chp; ++t) {
    float gnext = 0.0f;
    if (t + 1 < chp) gnext = gates[gbase + (size_t)(t + 1) * 32 * N4];

    float a0 = 0.f, a1 = 0.f;
#pragma unroll
    for (int k4 = 0; k4 < 16; ++k4) {
      float4 h0 = *(const float4*)&hbuf[k4 * 4];
      float4 h1 = *(const float4*)&hbuf[64 + k4 * 4];
      a0 = fmaf(W[k4 * 4 + 0], h0.x, a0); a0 = fmaf(W[k4 * 4 + 1], h0.y, a0);
      a0 = fmaf(W[k4 * 4 + 2], h0.z, a0); a0 = fmaf(W[k4 * 4 + 3], h0.w, a0);
      a1 = fmaf(W[64 + k4 * 4 + 0], h1.x, a1); a1 = fmaf(W[64 + k4 * 4 + 1], h1.y, a1);
      a1 = fmaf(W[64 + k4 * 4 + 2], h1.z, a1); a1 = fmaf(W[64 + k4 * 4 + 3], h1.w, a1);
    }
    float pv = gcur + (a0 + a1);
    // owner-side nonlinearities (wave-uniform branch, overlaps across waves)
    if (g == 2) pv = fast_tanh(pv);
    else if (g == 3) pv = fast_sigmoid(pv);
    pre[tid] = pv;
    __syncthreads();

    if (tid < 128) {
      float iv = pre[tid], fv = pre[128 + tid];
      float zt = pre[256 + tid], og = pre[384 + tid];   // already tanh'd / sigmoid'd
      float a = fv + m;
      float mn = fmaxf(a, iv);
      float fe = __expf(a - mn);
      float ie = __expf(iv - mn);
      c = fe * c + ie * zt;
      nn = fe * nn + ie;
      m = mn;
      float h = og * (c / nn);
      out[(size_t)(t0 + t) * (BB * HH) + (size_t)b * HH + head * HSS + tid] = h;
      hbuf[tid] = h;
    }
    __syncthreads();
    gcur = gnext;
  }

  if (tid < 128) {
    int si = (b * NHH + head) * HSS + tid;
    stc[si] = c; stn[si] = nn; stm[si] = m;
    hst[si] = hbuf[tid];
  }
}

// ---------------- launcher ----------------
// ws: whhT 2MB | stc/stn/stm 128KB ea | hst 128KB | Bh/Bl 8MB ea |
//     Ah/Al ch*64KB ea | gates ch*512KB
extern "C" void kernel_launch(void* const* d_in, const int* in_sizes, int n_in,
                              void* d_out, int out_size, void* d_ws, size_t ws_size,
                              hipStream_t stream) {
  const float* xs   = (const float*)d_in[0];
  const float* wih  = (const float*)d_in[1];
  const float* whh  = (const float*)d_in[2];
  const float* bias = (const float*)d_in[3];
  float* out = (float*)d_out;
  char* ws = (char*)d_ws;

  float* whhT = (float*)(ws + 0);
  float* stc  = (float*)(ws + 2097152);
  float* stn  = (float*)(ws + 2228224);
  float* stm  = (float*)(ws + 2359296);
  float* hst  = (float*)(ws + 2490368);
  _Float16* Bh = (_Float16*)(ws + 2621440);    // 4096*1024*2 = 8388608
  _Float16* Bl = (_Float16*)(ws + 11010048);   // + 8388608 -> ends 19398656
  const size_t base = 19398656;

  // per-chunk: Ah + Al = ch*131072 B, gates = ch*524288 B
  int ch = 256;
  while (ch > 8 && base + (size_t)ch * 655360 > ws_size) ch >>= 1;
  _Float16* Ahp = (_Float16*)(ws + base);
  _Float16* Alp = (_Float16*)(ws + base + (size_t)ch * 65536);
  float* gts = (float*)(ws + base + (size_t)ch * 131072);
  const int nch = TT / ch;

  prep_kernel<<<256, 256, 0, stream>>>(whh, whhT, stc, hst);
  convert_split<<<1024, 256, 0, stream>>>(wih, Bh, Bl, N4 * II / 4);

  for (int cix = 0; cix < nch; ++cix) {
    convert_split<<<1024, 256, 0, stream>>>(xs + (size_t)cix * ch * BB * II,
                                            Ahp, Alp, ch * BB * II / 4);
    dim3 g(32, (unsigned)(ch * 32 / 128));
    gemm_gates_mfma<<<g, 256, 0, stream>>>(Ahp, Alp, Bh, Bl, bias, gts);
    scan_f32<<<256, 512, 0, stream>>>(gts, whhT, out, stc, stn, stm, hst,
                                      cix * ch, ch);
  }
}